// Round 3
// baseline (211.477 us; speedup 1.0000x reference)
//
#include <hip/hip_runtime.h>
#include <math.h>

// S[c0,c1] = sum_kk (w[kk>>8]*W0[kk,c0]) * W1[kk,c1],  kk in [0,65536)
// out[b] = log(S[x0[b], x1[b]])
//
// gemm: 256 blocks (1/CU), one split of 256 kk each (= exactly one latent k
// -> w_sum scale is a block-uniform scalar). Each block computes the FULL
// 256x256 tile -> every byte of W is read by exactly one block (134 MB total,
// the read-once floor). Register-prefetch + double-buffered LDS pipeline
// keeps HBM busy across the convert/MFMA phases.

#define SPLITS  256
#define KCHUNK  256
#define BK      32
#define NITER   (KCHUNK / BK)   // 8
#define LDSS    40              // shorts per c-row: 32 k + 8 pad = 80 B

typedef float  f32x4  __attribute__((ext_vector_type(4)));
typedef short  bf16x8 __attribute__((ext_vector_type(8)));

static __device__ __forceinline__ short f2bf(float f) {
    // RNE fp32 -> bf16 (inputs are positive probabilities; no NaN/Inf)
    unsigned u = __builtin_bit_cast(unsigned, f);
    u += 0x7fffu + ((u >> 16) & 1u);
    return (short)(u >> 16);
}

template <bool USE_PART>
__global__ __launch_bounds__(512, 2) void gemm_s_kernel(
    const float* __restrict__ W, const float* __restrict__ wsum,
    float* __restrict__ out_acc)
{
    __shared__ short As[2][256 * LDSS];   // [buf][c0][k]  20 KB each
    __shared__ short Bs[2][256 * LDSS];   // [buf][c1][k]

    const int  split = blockIdx.x;             // 0..255
    const long kbase = (long)split * KCHUNK;
    const float wk   = wsum[split];            // block-uniform

    const float* __restrict__ Ag = W + kbase * 256;              // W0 rows
    const float* __restrict__ Bg = W + 16777216 + kbase * 256;   // W1 rows

    const int t  = threadIdx.x;
    const int cq = (t & 63) * 4;    // c-quad this thread stages
    const int kq = (t >> 6) * 4;    // k-quad (0..28)

    const int lane = t & 63;
    const int wv   = t >> 6;             // wave 0..7
    const int wc0  = (wv & 3) * 64;      // 4 wave-tiles along c0
    const int wc1  = (wv >> 2) * 128;    // 2 along c1
    const int ml   = lane & 15;
    const int qd   = lane >> 4;

    f32x4 acc[4][8];
#pragma unroll
    for (int i = 0; i < 4; ++i)
#pragma unroll
        for (int j = 0; j < 8; ++j) acc[i][j] = (f32x4){0.f, 0.f, 0.f, 0.f};

    float4 a4[4], b4[4];

    // ---- prologue: load + stage iter 0 ----
#pragma unroll
    for (int r = 0; r < 4; ++r) {
        a4[r] = *(const float4*)(Ag + (long)(kq + r) * 256 + cq);
        b4[r] = *(const float4*)(Bg + (long)(kq + r) * 256 + cq);
    }
    {
        const float* af32 = reinterpret_cast<const float*>(a4);
        const float* bf32 = reinterpret_cast<const float*>(b4);
#pragma unroll
        for (int j = 0; j < 4; ++j) {
            short4 av, bv;
            av.x = f2bf(af32[0 * 4 + j] * wk);
            av.y = f2bf(af32[1 * 4 + j] * wk);
            av.z = f2bf(af32[2 * 4 + j] * wk);
            av.w = f2bf(af32[3 * 4 + j] * wk);
            bv.x = f2bf(bf32[0 * 4 + j]);
            bv.y = f2bf(bf32[1 * 4 + j]);
            bv.z = f2bf(bf32[2 * 4 + j]);
            bv.w = f2bf(bf32[3 * 4 + j]);
            *(short4*)&As[0][(cq + j) * LDSS + kq] = av;
            *(short4*)&Bs[0][(cq + j) * LDSS + kq] = bv;
        }
    }
    __syncthreads();

    // ---- pipelined main loop ----
#pragma unroll
    for (int it = 0; it < NITER; ++it) {
        const int cur = it & 1;
        // issue next iter's global loads FIRST (stay in flight over the MFMAs)
        if (it + 1 < NITER) {
#pragma unroll
            for (int r = 0; r < 4; ++r) {
                a4[r] = *(const float4*)(Ag + (long)((it + 1) * BK + kq + r) * 256 + cq);
                b4[r] = *(const float4*)(Bg + (long)((it + 1) * BK + kq + r) * 256 + cq);
            }
        }
        // compute current tile from LDS
        bf16x8 afr[4];
#pragma unroll
        for (int mi = 0; mi < 4; ++mi)
            afr[mi] = *(const bf16x8*)&As[cur][(wc0 + mi * 16 + ml) * LDSS + qd * 8];
#pragma unroll
        for (int ni = 0; ni < 8; ++ni) {
            const bf16x8 bfr = *(const bf16x8*)&Bs[cur][(wc1 + ni * 16 + ml) * LDSS + qd * 8];
#pragma unroll
            for (int mi = 0; mi < 4; ++mi)
                acc[mi][ni] = __builtin_amdgcn_mfma_f32_16x16x32_bf16(
                    afr[mi], bfr, acc[mi][ni], 0, 0, 0);
        }
        // convert + stage into the other buffer
        if (it + 1 < NITER) {
            const float* af32 = reinterpret_cast<const float*>(a4);
            const float* bf32 = reinterpret_cast<const float*>(b4);
#pragma unroll
            for (int j = 0; j < 4; ++j) {
                short4 av, bv;
                av.x = f2bf(af32[0 * 4 + j] * wk);
                av.y = f2bf(af32[1 * 4 + j] * wk);
                av.z = f2bf(af32[2 * 4 + j] * wk);
                av.w = f2bf(af32[3 * 4 + j] * wk);
                bv.x = f2bf(bf32[0 * 4 + j]);
                bv.y = f2bf(bf32[1 * 4 + j]);
                bv.z = f2bf(bf32[2 * 4 + j]);
                bv.w = f2bf(bf32[3 * 4 + j]);
                *(short4*)&As[1 - cur][(cq + j) * LDSS + kq] = av;
                *(short4*)&Bs[1 - cur][(cq + j) * LDSS + kq] = bv;
            }
            __syncthreads();
        }
    }

    // ---- epilogue. C/D layout: col = lane&15, row = (lane>>4)*4 + reg ----
    if (USE_PART) {
        float* __restrict__ Pb = out_acc + (size_t)split * 65536;
#pragma unroll
        for (int mi = 0; mi < 4; ++mi) {
            const int row0 = wc0 + mi * 16 + qd * 4;
#pragma unroll
            for (int ni = 0; ni < 8; ++ni) {
                const int col = wc1 + ni * 16 + ml;
#pragma unroll
                for (int r = 0; r < 4; ++r)
                    Pb[(row0 + r) * 256 + col] = acc[mi][ni][r];
            }
        }
    } else {
#pragma unroll
        for (int mi = 0; mi < 4; ++mi) {
            const int row0 = wc0 + mi * 16 + qd * 4;
#pragma unroll
            for (int ni = 0; ni < 8; ++ni) {
                const int col = wc1 + ni * 16 + ml;
#pragma unroll
                for (int r = 0; r < 4; ++r)
                    atomicAdd(&out_acc[(row0 + r) * 256 + col], acc[mi][ni][r]);
            }
        }
    }
}

// One wave per b: lanes sum the 256 split partials (4 each), shuffle-reduce, log.
__global__ __launch_bounds__(64) void finish_part_kernel(
    const int* __restrict__ x, const float* __restrict__ P, float* __restrict__ out)
{
    const int b  = blockIdx.x;
    const int t  = threadIdx.x;        // 0..63
    const int x0 = x[2 * b], x1 = x[2 * b + 1];
    const size_t base = (size_t)x0 * 256 + x1;
    float v = 0.f;
#pragma unroll
    for (int j = 0; j < 4; ++j)
        v += P[(size_t)(t + 64 * j) * 65536 + base];
#pragma unroll
    for (int off = 32; off > 0; off >>= 1) v += __shfl_down(v, off);
    if (t == 0) out[b] = logf(v);
}

__global__ __launch_bounds__(64) void finish_atom_kernel(
    const int* __restrict__ x, const float* __restrict__ S, float* __restrict__ out)
{
    const int b  = blockIdx.x * 64 + threadIdx.x;   // 16 x 64 = 1024
    const int x0 = x[2 * b], x1 = x[2 * b + 1];
    out[b] = logf(S[x0 * 256 + x1]);
}

extern "C" void kernel_launch(void* const* d_in, const int* in_sizes, int n_in,
                              void* d_out, int out_size, void* d_ws, size_t ws_size,
                              hipStream_t stream)
{
    const int*   x    = (const int*)d_in[0];     // [1024,2] int32
    const float* W    = (const float*)d_in[1];   // [2,256,256,256] fp32
    const float* wsum = (const float*)d_in[2];   // [256] fp32
    float* out = (float*)d_out;                  // [1024] fp32

    const size_t part_bytes = (size_t)SPLITS * 65536 * sizeof(float); // 67 MB

    if (ws_size >= part_bytes) {
        float* P = (float*)d_ws;
        gemm_s_kernel<true><<<dim3(SPLITS), 512, 0, stream>>>(W, wsum, P);
        finish_part_kernel<<<dim3(1024), 64, 0, stream>>>(x, P, out);
    } else {
        float* S = (float*)d_ws;                 // 256 KB, must be zeroed
        hipMemsetAsync(d_ws, 0, 65536 * sizeof(float), stream);
        gemm_s_kernel<false><<<dim3(SPLITS), 512, 0, stream>>>(W, wsum, S);
        finish_atom_kernel<<<dim3(16), 64, 0, stream>>>(x, S, out);
    }
}